// Round 1
// baseline (411.327 us; speedup 1.0000x reference)
//
#include <hip/hip_runtime.h>
#include <math.h>

#define NV 8192
#define NE 4096
#define DIN 512
#define DH 256
#define CAP_E 96
#define CAP_V 64

// ---------------- workspace layout (float offsets) ----------------
#define OFF_XH   0                       // V*DH
#define OFF_XN   (OFF_XH + NV*DH)        // V*DH
#define OFF_Z    (OFF_XN + NV*DH)        // V*DH
#define OFF_Y    (OFF_Z  + NV*DH)        // E*DH
#define OFF_DVI  (OFF_Y  + NE*DH)        // V
#define OFF_DEI  (OFF_DVI + NV)          // E
#define OFF_NCNT (OFF_DEI + NE)          // V ints
#define OFF_ECNT (OFF_NCNT + NV)         // E ints
#define OFF_EL   (OFF_ECNT + NE)         // E*CAP_E ints
#define OFF_NL   (OFF_EL + NE*CAP_E)     // V*CAP_V ints

// ---------------- build sparse adjacency from dense H ----------------
__global__ __launch_bounds__(256) void scan_H(const float* __restrict__ H,
                                              int* __restrict__ edge_cnt,
                                              int* __restrict__ node_cnt,
                                              int* __restrict__ edge_list,
                                              int* __restrict__ node_list) {
    int idx = blockIdx.x * 256 + threadIdx.x;   // one float4 per thread
    int f0 = idx * 4;
    int v = f0 >> 12;          // / NE (4096)
    int e = f0 & (NE - 1);
    float4 h = *(const float4*)(H + (size_t)f0);
    float hv[4] = {h.x, h.y, h.z, h.w};
#pragma unroll
    for (int j = 0; j < 4; ++j) {
        if (hv[j] != 0.0f) {
            int ee = e + j;
            int s1 = atomicAdd(&edge_cnt[ee], 1);
            if (s1 < CAP_E) edge_list[ee * CAP_E + s1] = v;
            int s2 = atomicAdd(&node_cnt[v], 1);
            if (s2 < CAP_V) node_list[v * CAP_V + s2] = ee;
        }
    }
}

__global__ __launch_bounds__(256) void inv_sqrt_deg(const int* __restrict__ node_cnt,
                                                    const int* __restrict__ edge_cnt,
                                                    float* __restrict__ dvi,
                                                    float* __restrict__ dei) {
    int i = blockIdx.x * 256 + threadIdx.x;
    if (i < NV) { int c = node_cnt[i]; dvi[i] = c > 0 ? 1.0f / sqrtf((float)c) : 0.0f; }
    if (i < NE) { int c = edge_cnt[i]; dei[i] = c > 0 ? 1.0f / sqrtf((float)c) : 0.0f; }
}

// ---------------- tiled fp32 GEMM: C[M,N] = A[M,K] @ B[N,K]^T (opt relu) ----------------
template<bool RELU>
__global__ __launch_bounds__(256) void gemm_nt(const float* __restrict__ A,
                                               const float* __restrict__ B,
                                               float* __restrict__ C,
                                               int M, int N, int K) {
    const int BM = 64, BN = 64, BK = 32, LD = BM + 4;  // LD=68: b128-aligned, 2-way reads
    __shared__ float As[BK][LD];
    __shared__ float Bs[BK][LD];
    int bm = blockIdx.y * BM;
    int bn = blockIdx.x * BN;
    int tid = threadIdx.x;
    int tx = tid & 15, ty = tid >> 4;
    float acc[4][4] = {};
    for (int k0 = 0; k0 < K; k0 += BK) {
#pragma unroll
        for (int it = 0; it < 2; ++it) {
            int idx = tid + it * 256;       // 0..511
            int row = idx >> 3;             // 0..63
            int kq  = idx & 7;              // float4 slot in K
            float4 a4 = *(const float4*)(A + (size_t)(bm + row) * K + k0 + kq * 4);
            As[kq*4+0][row] = a4.x; As[kq*4+1][row] = a4.y;
            As[kq*4+2][row] = a4.z; As[kq*4+3][row] = a4.w;
            float4 b4 = *(const float4*)(B + (size_t)(bn + row) * K + k0 + kq * 4);
            Bs[kq*4+0][row] = b4.x; Bs[kq*4+1][row] = b4.y;
            Bs[kq*4+2][row] = b4.z; Bs[kq*4+3][row] = b4.w;
        }
        __syncthreads();
#pragma unroll
        for (int kk = 0; kk < BK; ++kk) {
            float4 a = *(const float4*)&As[kk][ty * 4];
            float4 b = *(const float4*)&Bs[kk][tx * 4];
            float av[4] = {a.x, a.y, a.z, a.w};
            float bv[4] = {b.x, b.y, b.z, b.w};
#pragma unroll
            for (int i = 0; i < 4; ++i)
#pragma unroll
                for (int j = 0; j < 4; ++j)
                    acc[i][j] = fmaf(av[i], bv[j], acc[i][j]);
        }
        __syncthreads();
    }
#pragma unroll
    for (int i = 0; i < 4; ++i) {
        float4 o;
        float* p = &acc[i][0];
        o.x = p[0]; o.y = p[1]; o.z = p[2]; o.w = p[3];
        if (RELU) {
            o.x = fmaxf(o.x, 0.f); o.y = fmaxf(o.y, 0.f);
            o.z = fmaxf(o.z, 0.f); o.w = fmaxf(o.w, 0.f);
        }
        *(float4*)(C + (size_t)(bm + ty * 4 + i) * N + bn + tx * 4) = o;
    }
}

// ---------------- Y[e,:] = dei[e] * sum_{v in e} dvi[v] * Xh[v,:] ----------------
__global__ __launch_bounds__(256) void edge_gather(const float* __restrict__ Xh,
                                                   const int* __restrict__ edge_cnt,
                                                   const int* __restrict__ edge_list,
                                                   const float* __restrict__ dvi,
                                                   const float* __restrict__ dei,
                                                   float* __restrict__ Y) {
    int e = blockIdx.x;
    int tid = threadIdx.x;
    __shared__ int   lv[CAP_E];
    __shared__ float lc[CAP_E];
    int cnt = min(edge_cnt[e], CAP_E);
    if (tid < cnt) { int v = edge_list[e * CAP_E + tid]; lv[tid] = v * DH; lc[tid] = dvi[v]; }
    __syncthreads();
    float acc = 0.f;
    for (int i = 0; i < cnt; ++i) acc = fmaf(lc[i], Xh[lv[i] + tid], acc);
    Y[e * DH + tid] = dei[e] * acc;
}

// ---------------- Z[v,:] = dvi[v] * sum_{e ∋ v} dei[e] * Y[e,:] ----------------
__global__ __launch_bounds__(256) void node_gather(const float* __restrict__ Y,
                                                   const int* __restrict__ node_cnt,
                                                   const int* __restrict__ node_list,
                                                   const float* __restrict__ dei,
                                                   const float* __restrict__ dvi,
                                                   float* __restrict__ Z) {
    int v = blockIdx.x;
    int tid = threadIdx.x;
    __shared__ int   le[CAP_V];
    __shared__ float lc[CAP_V];
    int cnt = min(node_cnt[v], CAP_V);
    if (tid < cnt) { int e = node_list[v * CAP_V + tid]; le[tid] = e * DH; lc[tid] = dei[e]; }
    __syncthreads();
    float acc = 0.f;
    for (int i = 0; i < cnt; ++i) acc = fmaf(lc[i], Y[le[i] + tid], acc);
    Z[v * DH + tid] = dvi[v] * acc;
}

// ---------------- Xh = LayerNorm(Xh + Xn) * g + b, in place ----------------
__global__ __launch_bounds__(256) void residual_ln(float* __restrict__ Xh,
                                                   const float* __restrict__ Xn,
                                                   const float* __restrict__ g,
                                                   const float* __restrict__ b) {
    int row = blockIdx.x;
    int tid = threadIdx.x;
    __shared__ float red[4];
    float x = Xh[row * DH + tid] + Xn[row * DH + tid];
    float s = x;
#pragma unroll
    for (int o = 32; o > 0; o >>= 1) s += __shfl_down(s, o, 64);
    if ((tid & 63) == 0) red[tid >> 6] = s;
    __syncthreads();
    float m = (red[0] + red[1] + red[2] + red[3]) * (1.0f / DH);
    float d = x - m;
    float s2 = d * d;
#pragma unroll
    for (int o = 32; o > 0; o >>= 1) s2 += __shfl_down(s2, o, 64);
    __syncthreads();
    if ((tid & 63) == 0) red[tid >> 6] = s2;
    __syncthreads();
    float var = (red[0] + red[1] + red[2] + red[3]) * (1.0f / DH);
    float rstd = 1.0f / sqrtf(var + 1e-5f);
    Xh[row * DH + tid] = d * rstd * g[tid] + b[tid];
}

// ---------------- z_E[e,:] = mean over members of Xh ----------------
__global__ __launch_bounds__(256) void edge_pool(const float* __restrict__ Xh,
                                                 const int* __restrict__ edge_cnt,
                                                 const int* __restrict__ edge_list,
                                                 float* __restrict__ Y) {
    int e = blockIdx.x;
    int tid = threadIdx.x;
    __shared__ int lv[CAP_E];
    int cnt = min(edge_cnt[e], CAP_E);
    if (tid < cnt) lv[tid] = edge_list[e * CAP_E + tid] * DH;
    __syncthreads();
    float acc = 0.f;
    for (int i = 0; i < cnt; ++i) acc += Xh[lv[i] + tid];
    float inv = cnt > 0 ? 1.0f / (float)cnt : 1.0f;
    Y[e * DH + tid] = acc * inv;
}

// ---------------- logits + softmax, one wave per edge ----------------
__global__ __launch_bounds__(256) void classify(const float* __restrict__ zE,
                                                const float* __restrict__ Wc,
                                                const float* __restrict__ bc,
                                                float* __restrict__ out) {
    int e = blockIdx.x * 4 + (threadIdx.x >> 6);
    int lane = threadIdx.x & 63;
    float s0 = 0.f, s1 = 0.f;
#pragma unroll
    for (int d = lane; d < DH; d += 64) {
        float z = zE[e * DH + d];
        s0 = fmaf(z, Wc[d], s0);
        s1 = fmaf(z, Wc[DH + d], s1);
    }
#pragma unroll
    for (int o = 32; o > 0; o >>= 1) {
        s0 += __shfl_down(s0, o, 64);
        s1 += __shfl_down(s1, o, 64);
    }
    if (lane == 0) {
        float l0 = s0 + bc[0], l1 = s1 + bc[1];
        float mx = fmaxf(l0, l1);
        float e0 = expf(l0 - mx), e1 = expf(l1 - mx);
        float inv = 1.0f / (e0 + e1);
        out[e * 2 + 0] = e0 * inv;
        out[e * 2 + 1] = e1 * inv;
    }
}

extern "C" void kernel_launch(void* const* d_in, const int* in_sizes, int n_in,
                              void* d_out, int out_size, void* d_ws, size_t ws_size,
                              hipStream_t stream) {
    const float* X  = (const float*)d_in[0];
    const float* H  = (const float*)d_in[1];
    const float* Wp = (const float*)d_in[2];
    const float* W0 = (const float*)d_in[3];
    const float* W1 = (const float*)d_in[4];
    const float* g0 = (const float*)d_in[5];
    const float* b0 = (const float*)d_in[6];
    const float* g1 = (const float*)d_in[7];
    const float* b1 = (const float*)d_in[8];
    const float* Wc = (const float*)d_in[9];
    const float* bc = (const float*)d_in[10];
    float* out = (float*)d_out;

    float* ws = (float*)d_ws;
    float* Xh  = ws + OFF_XH;
    float* Xn  = ws + OFF_XN;
    float* Z   = ws + OFF_Z;
    float* Y   = ws + OFF_Y;
    float* dvi = ws + OFF_DVI;
    float* dei = ws + OFF_DEI;
    int* node_cnt  = (int*)(ws + OFF_NCNT);
    int* edge_cnt  = (int*)(ws + OFF_ECNT);
    int* edge_list = (int*)(ws + OFF_EL);
    int* node_list = (int*)(ws + OFF_NL);

    // zero the counters (node_cnt and edge_cnt are adjacent)
    hipMemsetAsync(node_cnt, 0, (size_t)(NV + NE) * sizeof(int), stream);

    // build adjacency + degrees
    scan_H<<<(NV * NE) / 1024, 256, 0, stream>>>(H, edge_cnt, node_cnt, edge_list, node_list);
    inv_sqrt_deg<<<NV / 256, 256, 0, stream>>>(node_cnt, edge_cnt, dvi, dei);

    // Xh = X @ Wp^T   (V x DIN) @ (DIN x DH)
    gemm_nt<false><<<dim3(DH / 64, NV / 64), 256, 0, stream>>>(X, Wp, Xh, NV, DH, DIN);

    const float* Ws[2] = {W0, W1};
    const float* gs[2] = {g0, g1};
    const float* bs[2] = {b0, b1};
    for (int l = 0; l < 2; ++l) {
        edge_gather<<<NE, 256, 0, stream>>>(Xh, edge_cnt, edge_list, dvi, dei, Y);
        node_gather<<<NV, 256, 0, stream>>>(Y, node_cnt, node_list, dei, dvi, Z);
        gemm_nt<true><<<dim3(DH / 64, NV / 64), 256, 0, stream>>>(Z, Ws[l], Xn, NV, DH, DH);
        residual_ln<<<NV, 256, 0, stream>>>(Xh, Xn, gs[l], bs[l]);
    }

    // mean-pool per edge into Y, then classify
    edge_pool<<<NE, 256, 0, stream>>>(Xh, edge_cnt, edge_list, Y);
    classify<<<NE / 4, 256, 0, stream>>>(Y, Wc, bc, out);
}

// Round 2
// 380.505 us; speedup vs baseline: 1.0810x; 1.0810x over previous
//
#include <hip/hip_runtime.h>
#include <math.h>

#define NV 8192
#define NE 4096
#define DIN 512
#define DH 256
#define CAP_E 96
#define CAP_V 64

// ---------------- workspace layout (float offsets) ----------------
#define OFF_XH   0                       // V*DH
#define OFF_XN   (OFF_XH + NV*DH)        // V*DH
#define OFF_Z    (OFF_XN + NV*DH)        // V*DH
#define OFF_Y    (OFF_Z  + NV*DH)        // E*DH
#define OFF_DVI  (OFF_Y  + NE*DH)        // V
#define OFF_DEI  (OFF_DVI + NV)          // E
#define OFF_NCNT (OFF_DEI + NE)          // V ints
#define OFF_ECNT (OFF_NCNT + NV)         // E ints
#define OFF_EL   (OFF_ECNT + NE)         // E*CAP_E ints
#define OFF_NL   (OFF_EL + NE*CAP_E)     // V*CAP_V ints

using bf16x8 = __attribute__((ext_vector_type(8))) short;
using f32x4  = __attribute__((ext_vector_type(4))) float;

__device__ inline unsigned short f2bf(float f) {   // round-to-nearest-even
    union { float f; unsigned u; } v; v.f = f;
    unsigned r = v.u + 0x7FFF + ((v.u >> 16) & 1);
    return (unsigned short)(r >> 16);
}

// ---------------- build sparse adjacency from dense H ----------------
__global__ __launch_bounds__(256) void scan_H(const float* __restrict__ H,
                                              int* __restrict__ edge_cnt,
                                              int* __restrict__ node_cnt,
                                              int* __restrict__ edge_list,
                                              int* __restrict__ node_list) {
    int idx = blockIdx.x * 256 + threadIdx.x;   // one float4 per thread
    int f0 = idx * 4;
    int v = f0 >> 12;          // / NE (4096)
    int e = f0 & (NE - 1);
    float4 h = *(const float4*)(H + (size_t)f0);
    float hv[4] = {h.x, h.y, h.z, h.w};
    bool any = (hv[0] != 0.f) || (hv[1] != 0.f) || (hv[2] != 0.f) || (hv[3] != 0.f);
    if (__ballot(any) == 0ull) return;   // whole wave empty (common at 0.4% density)
#pragma unroll
    for (int j = 0; j < 4; ++j) {
        if (hv[j] != 0.0f) {
            int ee = e + j;
            int s1 = atomicAdd(&edge_cnt[ee], 1);
            if (s1 < CAP_E) edge_list[ee * CAP_E + s1] = v;
            int s2 = atomicAdd(&node_cnt[v], 1);
            if (s2 < CAP_V) node_list[v * CAP_V + s2] = ee;
        }
    }
}

__global__ __launch_bounds__(256) void inv_sqrt_deg(const int* __restrict__ node_cnt,
                                                    const int* __restrict__ edge_cnt,
                                                    float* __restrict__ dvi,
                                                    float* __restrict__ dei) {
    int i = blockIdx.x * 256 + threadIdx.x;
    if (i < NV) { int c = node_cnt[i]; dvi[i] = c > 0 ? 1.0f / sqrtf((float)c) : 0.0f; }
    if (i < NE) { int c = edge_cnt[i]; dei[i] = c > 0 ? 1.0f / sqrtf((float)c) : 0.0f; }
}

// ---------------- bf16 MFMA GEMM: C[M,256] = A[M,K] @ B[256,K]^T (opt relu) ----
// Tile: BM=32, BN=256 (full rows, A read once), BK=64. 256 thr = 4 waves.
// Wave w computes rows [bm,bm+32) x cols [w*64,(w+1)*64) via 2x4 quads of 16x16x32.
// LDS is fragment-major: granule(group, lane) so every read is a lane-sequential
// conflict-free ds_read_b128; lanes XOR-swizzled so staging writes spread banks.
template<bool RELU>
__global__ __launch_bounds__(256) void gemm_bf16(const float* __restrict__ A,
                                                 const float* __restrict__ B,
                                                 float* __restrict__ C,
                                                 int K) {
    __shared__ short As[2048];    // 2 msub x 2 kc groups x 512
    __shared__ short Bs[16384];   // 16 nsub x 2 kc groups x 512
    const int tid  = threadIdx.x;
    const int lane = tid & 63;
    const int w    = tid >> 6;
    const int bm   = blockIdx.x * 32;
    const int swz  = lane ^ ((lane >> 3) & 6);   // XOR bits[5:4] into [2:1]

    float4 ar[2], br[16];
    // prefetch tile k0=0
    {
        int i0 = tid, i1 = tid + 256;
        ar[0] = *(const float4*)(A + (size_t)(bm + (i0 >> 4)) * K + ((i0 & 15) << 2));
        ar[1] = *(const float4*)(A + (size_t)(bm + (i1 >> 4)) * K + ((i1 & 15) << 2));
#pragma unroll
        for (int it = 0; it < 16; ++it) {
            int i = tid + it * 256;
            br[it] = *(const float4*)(B + (size_t)(i >> 4) * K + ((i & 15) << 2));
        }
    }
    f32x4 acc[2][4];
#pragma unroll
    for (int mi = 0; mi < 2; ++mi)
#pragma unroll
        for (int ni = 0; ni < 4; ++ni) acc[mi][ni] = (f32x4){0.f, 0.f, 0.f, 0.f};

    for (int k0 = 0; k0 < K; k0 += 64) {
        __syncthreads();           // previous compute done reading LDS
        // regs -> LDS (fp32 -> bf16)
#pragma unroll
        for (int s = 0; s < 2; ++s) {
            int i = tid + s * 256;
            int row = i >> 4, kk = (i & 15) << 2;
            int kc = kk >> 5, quad = (kk >> 3) & 3, j = kk & 7;
            int ln = (row & 15) + (quad << 4);
            int p  = ln ^ ((ln >> 3) & 6);
            int addr = ((row >> 4) * 2 + kc) * 512 + p * 8 + j;
            float4 v = ar[s];
            ushort4 u = {f2bf(v.x), f2bf(v.y), f2bf(v.z), f2bf(v.w)};
            *(ushort4*)&As[addr] = u;
        }
#pragma unroll
        for (int it = 0; it < 16; ++it) {
            int i = tid + it * 256;
            int row = i >> 4, kk = (i & 15) << 2;
            int kc = kk >> 5, quad = (kk >> 3) & 3, j = kk & 7;
            int ln = (row & 15) + (quad << 4);
            int p  = ln ^ ((ln >> 3) & 6);
            int addr = ((row >> 4) * 2 + kc) * 512 + p * 8 + j;
            float4 v = br[it];
            ushort4 u = {f2bf(v.x), f2bf(v.y), f2bf(v.z), f2bf(v.w)};
            *(ushort4*)&Bs[addr] = u;
        }
        __syncthreads();
        // prefetch next tile while computing on this one
        if (k0 + 64 < K) {
            int kn = k0 + 64;
            int i0 = tid, i1 = tid + 256;
            ar[0] = *(const float4*)(A + (size_t)(bm + (i0 >> 4)) * K + kn + ((i0 & 15) << 2));
            ar[1] = *(const float4*)(A + (size_t)(bm + (i1 >> 4)) * K + kn + ((i1 & 15) << 2));
#pragma unroll
            for (int it = 0; it < 16; ++it) {
                int i = tid + it * 256;
                br[it] = *(const float4*)(B + (size_t)(i >> 4) * K + kn + ((i & 15) << 2));
            }
        }
#pragma unroll
        for (int kc = 0; kc < 2; ++kc) {
            bf16x8 af[2], bf[4];
            af[0] = *(const bf16x8*)&As[(0 * 2 + kc) * 512 + swz * 8];
            af[1] = *(const bf16x8*)&As[(1 * 2 + kc) * 512 + swz * 8];
#pragma unroll
            for (int ni = 0; ni < 4; ++ni)
                bf[ni] = *(const bf16x8*)&Bs[((w * 4 + ni) * 2 + kc) * 512 + swz * 8];
#pragma unroll
            for (int mi = 0; mi < 2; ++mi)
#pragma unroll
                for (int ni = 0; ni < 4; ++ni)
                    acc[mi][ni] = __builtin_amdgcn_mfma_f32_16x16x32_bf16(
                        af[mi], bf[ni], acc[mi][ni], 0, 0, 0);
        }
    }
    // epilogue: C/D layout col=lane&15, row=quad*4+reg
    const int quad = lane >> 4, cl = lane & 15;
#pragma unroll
    for (int mi = 0; mi < 2; ++mi)
#pragma unroll
        for (int ni = 0; ni < 4; ++ni)
#pragma unroll
            for (int r = 0; r < 4; ++r) {
                float v = acc[mi][ni][r];
                if (RELU) v = fmaxf(v, 0.f);
                C[(size_t)(bm + mi * 16 + quad * 4 + r) * DH + w * 64 + ni * 16 + cl] = v;
            }
}

// ---------------- Y[e,:] = dei[e] * sum_{v in e} dvi[v] * Xh[v,:] ----------------
__global__ __launch_bounds__(256) void edge_gather(const float* __restrict__ Xh,
                                                   const int* __restrict__ edge_cnt,
                                                   const int* __restrict__ edge_list,
                                                   const float* __restrict__ dvi,
                                                   const float* __restrict__ dei,
                                                   float* __restrict__ Y) {
    int e = blockIdx.x;
    int tid = threadIdx.x;
    __shared__ int   lv[CAP_E];
    __shared__ float lc[CAP_E];
    int cnt = min(edge_cnt[e], CAP_E);
    if (tid < cnt) { int v = edge_list[e * CAP_E + tid]; lv[tid] = v * DH; lc[tid] = dvi[v]; }
    __syncthreads();
    float a0 = 0.f, a1 = 0.f, a2 = 0.f, a3 = 0.f;
    int i = 0;
    for (; i + 4 <= cnt; i += 4) {
        a0 = fmaf(lc[i+0], Xh[lv[i+0] + tid], a0);
        a1 = fmaf(lc[i+1], Xh[lv[i+1] + tid], a1);
        a2 = fmaf(lc[i+2], Xh[lv[i+2] + tid], a2);
        a3 = fmaf(lc[i+3], Xh[lv[i+3] + tid], a3);
    }
    for (; i < cnt; ++i) a0 = fmaf(lc[i], Xh[lv[i] + tid], a0);
    Y[e * DH + tid] = dei[e] * ((a0 + a1) + (a2 + a3));
}

// ---------------- Z[v,:] = dvi[v] * sum_{e ∋ v} dei[e] * Y[e,:] ----------------
__global__ __launch_bounds__(256) void node_gather(const float* __restrict__ Y,
                                                   const int* __restrict__ node_cnt,
                                                   const int* __restrict__ node_list,
                                                   const float* __restrict__ dei,
                                                   const float* __restrict__ dvi,
                                                   float* __restrict__ Z) {
    int v = blockIdx.x;
    int tid = threadIdx.x;
    __shared__ int   le[CAP_V];
    __shared__ float lc[CAP_V];
    int cnt = min(node_cnt[v], CAP_V);
    if (tid < cnt) { int e = node_list[v * CAP_V + tid]; le[tid] = e * DH; lc[tid] = dei[e]; }
    __syncthreads();
    float a0 = 0.f, a1 = 0.f, a2 = 0.f, a3 = 0.f;
    int i = 0;
    for (; i + 4 <= cnt; i += 4) {
        a0 = fmaf(lc[i+0], Y[le[i+0] + tid], a0);
        a1 = fmaf(lc[i+1], Y[le[i+1] + tid], a1);
        a2 = fmaf(lc[i+2], Y[le[i+2] + tid], a2);
        a3 = fmaf(lc[i+3], Y[le[i+3] + tid], a3);
    }
    for (; i < cnt; ++i) a0 = fmaf(lc[i], Y[le[i] + tid], a0);
    Z[v * DH + tid] = dvi[v] * ((a0 + a1) + (a2 + a3));
}

// ---------------- Xh = LayerNorm(Xh + Xn) * g + b, in place ----------------
__global__ __launch_bounds__(256) void residual_ln(float* __restrict__ Xh,
                                                   const float* __restrict__ Xn,
                                                   const float* __restrict__ g,
                                                   const float* __restrict__ b) {
    int row = blockIdx.x;
    int tid = threadIdx.x;
    __shared__ float red[4];
    float x = Xh[row * DH + tid] + Xn[row * DH + tid];
    float s = x;
#pragma unroll
    for (int o = 32; o > 0; o >>= 1) s += __shfl_down(s, o, 64);
    if ((tid & 63) == 0) red[tid >> 6] = s;
    __syncthreads();
    float m = (red[0] + red[1] + red[2] + red[3]) * (1.0f / DH);
    float d = x - m;
    float s2 = d * d;
#pragma unroll
    for (int o = 32; o > 0; o >>= 1) s2 += __shfl_down(s2, o, 64);
    __syncthreads();
    if ((tid & 63) == 0) red[tid >> 6] = s2;
    __syncthreads();
    float var = (red[0] + red[1] + red[2] + red[3]) * (1.0f / DH);
    float rstd = 1.0f / sqrtf(var + 1e-5f);
    Xh[row * DH + tid] = d * rstd * g[tid] + b[tid];
}

// ---------------- fused mean-pool + classifier + softmax ----------------
__global__ __launch_bounds__(256) void pool_classify(const float* __restrict__ Xh,
                                                     const int* __restrict__ edge_cnt,
                                                     const int* __restrict__ edge_list,
                                                     const float* __restrict__ Wc,
                                                     const float* __restrict__ bc,
                                                     float* __restrict__ out) {
    int e = blockIdx.x;
    int tid = threadIdx.x;
    __shared__ int lv[CAP_E];
    __shared__ float red0[4], red1[4];
    int cnt = min(edge_cnt[e], CAP_E);
    if (tid < cnt) lv[tid] = edge_list[e * CAP_E + tid] * DH;
    __syncthreads();
    float a0 = 0.f, a1 = 0.f, a2 = 0.f, a3 = 0.f;
    int i = 0;
    for (; i + 4 <= cnt; i += 4) {
        a0 += Xh[lv[i+0] + tid]; a1 += Xh[lv[i+1] + tid];
        a2 += Xh[lv[i+2] + tid]; a3 += Xh[lv[i+3] + tid];
    }
    for (; i < cnt; ++i) a0 += Xh[lv[i] + tid];
    float inv = cnt > 0 ? 1.0f / (float)cnt : 1.0f;
    float val = ((a0 + a1) + (a2 + a3)) * inv;
    float p0 = val * Wc[tid];
    float p1 = val * Wc[DH + tid];
#pragma unroll
    for (int o = 32; o > 0; o >>= 1) {
        p0 += __shfl_down(p0, o, 64);
        p1 += __shfl_down(p1, o, 64);
    }
    if ((tid & 63) == 0) { red0[tid >> 6] = p0; red1[tid >> 6] = p1; }
    __syncthreads();
    if (tid == 0) {
        float l0 = red0[0] + red0[1] + red0[2] + red0[3] + bc[0];
        float l1 = red1[0] + red1[1] + red1[2] + red1[3] + bc[1];
        float mx = fmaxf(l0, l1);
        float e0 = expf(l0 - mx), e1 = expf(l1 - mx);
        float s = 1.0f / (e0 + e1);
        out[e * 2 + 0] = e0 * s;
        out[e * 2 + 1] = e1 * s;
    }
}

extern "C" void kernel_launch(void* const* d_in, const int* in_sizes, int n_in,
                              void* d_out, int out_size, void* d_ws, size_t ws_size,
                              hipStream_t stream) {
    const float* X  = (const float*)d_in[0];
    const float* H  = (const float*)d_in[1];
    const float* Wp = (const float*)d_in[2];
    const float* W0 = (const float*)d_in[3];
    const float* W1 = (const float*)d_in[4];
    const float* g0 = (const float*)d_in[5];
    const float* b0 = (const float*)d_in[6];
    const float* g1 = (const float*)d_in[7];
    const float* b1 = (const float*)d_in[8];
    const float* Wc = (const float*)d_in[9];
    const float* bc = (const float*)d_in[10];
    float* out = (float*)d_out;

    float* ws = (float*)d_ws;
    float* Xh  = ws + OFF_XH;
    float* Xn  = ws + OFF_XN;
    float* Z   = ws + OFF_Z;
    float* Y   = ws + OFF_Y;
    float* dvi = ws + OFF_DVI;
    float* dei = ws + OFF_DEI;
    int* node_cnt  = (int*)(ws + OFF_NCNT);
    int* edge_cnt  = (int*)(ws + OFF_ECNT);
    int* edge_list = (int*)(ws + OFF_EL);
    int* node_list = (int*)(ws + OFF_NL);

    hipMemsetAsync(node_cnt, 0, (size_t)(NV + NE) * sizeof(int), stream);

    scan_H<<<(NV * NE) / 1024, 256, 0, stream>>>(H, edge_cnt, node_cnt, edge_list, node_list);
    inv_sqrt_deg<<<NV / 256, 256, 0, stream>>>(node_cnt, edge_cnt, dvi, dei);

    // Xh = X @ Wp^T
    gemm_bf16<false><<<NV / 32, 256, 0, stream>>>(X, Wp, Xh, DIN);

    const float* Ws[2] = {W0, W1};
    const float* gs[2] = {g0, g1};
    const float* bs[2] = {b0, b1};
    for (int l = 0; l < 2; ++l) {
        edge_gather<<<NE, 256, 0, stream>>>(Xh, edge_cnt, edge_list, dvi, dei, Y);
        node_gather<<<NV, 256, 0, stream>>>(Y, node_cnt, node_list, dei, dvi, Z);
        gemm_bf16<true><<<NV / 32, 256, 0, stream>>>(Z, Ws[l], Xn, DH);
        residual_ln<<<NV, 256, 0, stream>>>(Xh, Xn, gs[l], bs[l]);
    }

    pool_classify<<<NE, 256, 0, stream>>>(Xh, edge_cnt, edge_list, Wc, bc, out);
}

// Round 3
// 329.690 us; speedup vs baseline: 1.2476x; 1.1541x over previous
//
#include <hip/hip_runtime.h>
#include <math.h>

#define NV 8192
#define NE 4096
#define DIN 512
#define DH 256
#define CAP_E 96
#define CAP_V 64

// ---------------- workspace layout (float offsets) ----------------
#define OFF_XH   0                       // V*DH
#define OFF_Z    (OFF_XH + NV*DH)        // V*DH
#define OFF_Y    (OFF_Z  + NV*DH)        // E*DH
#define OFF_NCNT (OFF_Y  + NE*DH)        // V ints
#define OFF_ECNT (OFF_NCNT + NV)         // E ints
#define OFF_EL   (OFF_ECNT + NE)         // E*CAP_E ints
#define OFF_NL   (OFF_EL + NE*CAP_E)     // V*CAP_V ints

using bf16x8 = __attribute__((ext_vector_type(8))) short;
using f32x4  = __attribute__((ext_vector_type(4))) float;

__device__ inline unsigned short f2bf(float f) {   // round-to-nearest-even
    union { float f; unsigned u; } v; v.f = f;
    unsigned r = v.u + 0x7FFF + ((v.u >> 16) & 1);
    return (unsigned short)(r >> 16);
}

// ---------------- build sparse adjacency from dense H ----------------
// 16 floats (4 x float4) per thread along the e-dimension.
__global__ __launch_bounds__(256) void scan_H(const float* __restrict__ H,
                                              int* __restrict__ edge_cnt,
                                              int* __restrict__ node_cnt,
                                              int* __restrict__ edge_list,
                                              int* __restrict__ node_list) {
    int idx = blockIdx.x * 256 + threadIdx.x;
    int f0 = idx * 16;
    int v = f0 >> 12;          // / NE (4096)
    int e = f0 & (NE - 1);
    float4 h0 = *(const float4*)(H + (size_t)f0);
    float4 h1 = *(const float4*)(H + (size_t)f0 + 4);
    float4 h2 = *(const float4*)(H + (size_t)f0 + 8);
    float4 h3 = *(const float4*)(H + (size_t)f0 + 12);
    float hv[16] = {h0.x, h0.y, h0.z, h0.w, h1.x, h1.y, h1.z, h1.w,
                    h2.x, h2.y, h2.z, h2.w, h3.x, h3.y, h3.z, h3.w};
    bool any = false;
#pragma unroll
    for (int j = 0; j < 16; ++j) any |= (hv[j] != 0.0f);
    if (__ballot(any) == 0ull) return;   // whole wave empty
#pragma unroll
    for (int j = 0; j < 16; ++j) {
        if (hv[j] != 0.0f) {
            int ee = e + j;
            int s1 = atomicAdd(&edge_cnt[ee], 1);
            if (s1 < CAP_E) edge_list[ee * CAP_E + s1] = v;
            int s2 = atomicAdd(&node_cnt[v], 1);
            if (s2 < CAP_V) node_list[v * CAP_V + s2] = ee;
        }
    }
}

// ---------------- bf16 MFMA GEMM (plain): C[M,256] = A[M,K] @ B[256,K]^T ------
// Tile BM=32, BN=256, BK=64; 256 thr = 4 waves; wave w owns cols [w*64,(w+1)*64).
__global__ __launch_bounds__(256) void gemm_bf16(const float* __restrict__ A,
                                                 const float* __restrict__ B,
                                                 float* __restrict__ C,
                                                 int K) {
    __shared__ short As[2048];
    __shared__ short Bs[16384];
    const int tid  = threadIdx.x;
    const int lane = tid & 63;
    const int w    = tid >> 6;
    const int bm   = blockIdx.x * 32;
    const int swz  = lane ^ ((lane >> 3) & 6);

    float4 ar[2], br[16];
    {
        int i0 = tid, i1 = tid + 256;
        ar[0] = *(const float4*)(A + (size_t)(bm + (i0 >> 4)) * K + ((i0 & 15) << 2));
        ar[1] = *(const float4*)(A + (size_t)(bm + (i1 >> 4)) * K + ((i1 & 15) << 2));
#pragma unroll
        for (int it = 0; it < 16; ++it) {
            int i = tid + it * 256;
            br[it] = *(const float4*)(B + (size_t)(i >> 4) * K + ((i & 15) << 2));
        }
    }
    f32x4 acc[2][4];
#pragma unroll
    for (int mi = 0; mi < 2; ++mi)
#pragma unroll
        for (int ni = 0; ni < 4; ++ni) acc[mi][ni] = (f32x4){0.f, 0.f, 0.f, 0.f};

    for (int k0 = 0; k0 < K; k0 += 64) {
        __syncthreads();
#pragma unroll
        for (int s = 0; s < 2; ++s) {
            int i = tid + s * 256;
            int row = i >> 4, kk = (i & 15) << 2;
            int kc = kk >> 5, quad = (kk >> 3) & 3, j = kk & 7;
            int ln = (row & 15) + (quad << 4);
            int p  = ln ^ ((ln >> 3) & 6);
            int addr = ((row >> 4) * 2 + kc) * 512 + p * 8 + j;
            float4 v = ar[s];
            ushort4 u = {f2bf(v.x), f2bf(v.y), f2bf(v.z), f2bf(v.w)};
            *(ushort4*)&As[addr] = u;
        }
#pragma unroll
        for (int it = 0; it < 16; ++it) {
            int i = tid + it * 256;
            int row = i >> 4, kk = (i & 15) << 2;
            int kc = kk >> 5, quad = (kk >> 3) & 3, j = kk & 7;
            int ln = (row & 15) + (quad << 4);
            int p  = ln ^ ((ln >> 3) & 6);
            int addr = ((row >> 4) * 2 + kc) * 512 + p * 8 + j;
            float4 v = br[it];
            ushort4 u = {f2bf(v.x), f2bf(v.y), f2bf(v.z), f2bf(v.w)};
            *(ushort4*)&Bs[addr] = u;
        }
        __syncthreads();
        if (k0 + 64 < K) {
            int kn = k0 + 64;
            int i0 = tid, i1 = tid + 256;
            ar[0] = *(const float4*)(A + (size_t)(bm + (i0 >> 4)) * K + kn + ((i0 & 15) << 2));
            ar[1] = *(const float4*)(A + (size_t)(bm + (i1 >> 4)) * K + kn + ((i1 & 15) << 2));
#pragma unroll
            for (int it = 0; it < 16; ++it) {
                int i = tid + it * 256;
                br[it] = *(const float4*)(B + (size_t)(i >> 4) * K + kn + ((i & 15) << 2));
            }
        }
#pragma unroll
        for (int kc = 0; kc < 2; ++kc) {
            bf16x8 af[2], bfr[4];
            af[0] = *(const bf16x8*)&As[(0 * 2 + kc) * 512 + swz * 8];
            af[1] = *(const bf16x8*)&As[(1 * 2 + kc) * 512 + swz * 8];
#pragma unroll
            for (int ni = 0; ni < 4; ++ni)
                bfr[ni] = *(const bf16x8*)&Bs[((w * 4 + ni) * 2 + kc) * 512 + swz * 8];
#pragma unroll
            for (int mi = 0; mi < 2; ++mi)
#pragma unroll
                for (int ni = 0; ni < 4; ++ni)
                    acc[mi][ni] = __builtin_amdgcn_mfma_f32_16x16x32_bf16(
                        af[mi], bfr[ni], acc[mi][ni], 0, 0, 0);
        }
    }
    const int quad = lane >> 4, cl = lane & 15;
#pragma unroll
    for (int mi = 0; mi < 2; ++mi)
#pragma unroll
        for (int ni = 0; ni < 4; ++ni)
#pragma unroll
            for (int r = 0; r < 4; ++r)
                C[(size_t)(bm + mi * 16 + quad * 4 + r) * DH + w * 64 + ni * 16 + cl]
                    = acc[mi][ni][r];
}

// ------- fused: Xh = LayerNorm(Xh + relu(Z @ W^T)) * g + b  (K=256) ----------
__global__ __launch_bounds__(256) void gemm_relu_res_ln(const float* __restrict__ Z,
                                                        const float* __restrict__ W,
                                                        float* __restrict__ Xh,
                                                        const float* __restrict__ g,
                                                        const float* __restrict__ b) {
    const int K = DH;
    __shared__ short As[2048];
    __shared__ short Bs[16384];
    __shared__ float redS[32][4];
    __shared__ float redQ[32][4];
    const int tid  = threadIdx.x;
    const int lane = tid & 63;
    const int w    = tid >> 6;
    const int bm   = blockIdx.x * 32;
    const int swz  = lane ^ ((lane >> 3) & 6);

    float4 ar[2], br[16];
    {
        int i0 = tid, i1 = tid + 256;
        ar[0] = *(const float4*)(Z + (size_t)(bm + (i0 >> 4)) * K + ((i0 & 15) << 2));
        ar[1] = *(const float4*)(Z + (size_t)(bm + (i1 >> 4)) * K + ((i1 & 15) << 2));
#pragma unroll
        for (int it = 0; it < 16; ++it) {
            int i = tid + it * 256;
            br[it] = *(const float4*)(W + (size_t)(i >> 4) * K + ((i & 15) << 2));
        }
    }
    f32x4 acc[2][4];
#pragma unroll
    for (int mi = 0; mi < 2; ++mi)
#pragma unroll
        for (int ni = 0; ni < 4; ++ni) acc[mi][ni] = (f32x4){0.f, 0.f, 0.f, 0.f};

    for (int k0 = 0; k0 < K; k0 += 64) {
        __syncthreads();
#pragma unroll
        for (int s = 0; s < 2; ++s) {
            int i = tid + s * 256;
            int row = i >> 4, kk = (i & 15) << 2;
            int kc = kk >> 5, quad = (kk >> 3) & 3, j = kk & 7;
            int ln = (row & 15) + (quad << 4);
            int p  = ln ^ ((ln >> 3) & 6);
            int addr = ((row >> 4) * 2 + kc) * 512 + p * 8 + j;
            float4 v = ar[s];
            ushort4 u = {f2bf(v.x), f2bf(v.y), f2bf(v.z), f2bf(v.w)};
            *(ushort4*)&As[addr] = u;
        }
#pragma unroll
        for (int it = 0; it < 16; ++it) {
            int i = tid + it * 256;
            int row = i >> 4, kk = (i & 15) << 2;
            int kc = kk >> 5, quad = (kk >> 3) & 3, j = kk & 7;
            int ln = (row & 15) + (quad << 4);
            int p  = ln ^ ((ln >> 3) & 6);
            int addr = ((row >> 4) * 2 + kc) * 512 + p * 8 + j;
            float4 v = br[it];
            ushort4 u = {f2bf(v.x), f2bf(v.y), f2bf(v.z), f2bf(v.w)};
            *(ushort4*)&Bs[addr] = u;
        }
        __syncthreads();
        if (k0 + 64 < K) {
            int kn = k0 + 64;
            int i0 = tid, i1 = tid + 256;
            ar[0] = *(const float4*)(Z + (size_t)(bm + (i0 >> 4)) * K + kn + ((i0 & 15) << 2));
            ar[1] = *(const float4*)(Z + (size_t)(bm + (i1 >> 4)) * K + kn + ((i1 & 15) << 2));
#pragma unroll
            for (int it = 0; it < 16; ++it) {
                int i = tid + it * 256;
                br[it] = *(const float4*)(W + (size_t)(i >> 4) * K + kn + ((i & 15) << 2));
            }
        }
#pragma unroll
        for (int kc = 0; kc < 2; ++kc) {
            bf16x8 af[2], bfr[4];
            af[0] = *(const bf16x8*)&As[(0 * 2 + kc) * 512 + swz * 8];
            af[1] = *(const bf16x8*)&As[(1 * 2 + kc) * 512 + swz * 8];
#pragma unroll
            for (int ni = 0; ni < 4; ++ni)
                bfr[ni] = *(const bf16x8*)&Bs[((w * 4 + ni) * 2 + kc) * 512 + swz * 8];
#pragma unroll
            for (int mi = 0; mi < 2; ++mi)
#pragma unroll
                for (int ni = 0; ni < 4; ++ni)
                    acc[mi][ni] = __builtin_amdgcn_mfma_f32_16x16x32_bf16(
                        af[mi], bfr[ni], acc[mi][ni], 0, 0, 0);
        }
    }
    // ---- fused epilogue: x = Xh + relu(acc); LayerNorm rows; write Xh ----
    const int quad = lane >> 4, cl = lane & 15;
#pragma unroll
    for (int mi = 0; mi < 2; ++mi)
#pragma unroll
        for (int r = 0; r < 4; ++r) {
            int row = bm + mi * 16 + quad * 4 + r;
            float s = 0.f, q = 0.f;
#pragma unroll
            for (int ni = 0; ni < 4; ++ni) {
                int col = w * 64 + ni * 16 + cl;
                float v = fmaxf(acc[mi][ni][r], 0.f) + Xh[(size_t)row * DH + col];
                acc[mi][ni][r] = v;
                s += v; q = fmaf(v, v, q);
            }
#pragma unroll
            for (int o = 1; o < 16; o <<= 1) {
                s += __shfl_xor(s, o, 64);
                q += __shfl_xor(q, o, 64);
            }
            if (cl == 0) {
                redS[mi * 16 + quad * 4 + r][w] = s;
                redQ[mi * 16 + quad * 4 + r][w] = q;
            }
        }
    __syncthreads();
#pragma unroll
    for (int mi = 0; mi < 2; ++mi)
#pragma unroll
        for (int r = 0; r < 4; ++r) {
            int R = mi * 16 + quad * 4 + r;
            float s = redS[R][0] + redS[R][1] + redS[R][2] + redS[R][3];
            float q = redQ[R][0] + redQ[R][1] + redQ[R][2] + redQ[R][3];
            float m = s * (1.0f / DH);
            float var = q * (1.0f / DH) - m * m;
            float rstd = rsqrtf(var + 1e-5f);
            int row = bm + R;
#pragma unroll
            for (int ni = 0; ni < 4; ++ni) {
                int col = w * 64 + ni * 16 + cl;
                float v = (acc[mi][ni][r] - m) * rstd * g[col] + b[col];
                Xh[(size_t)row * DH + col] = v;
            }
        }
}

// ---- Y[e,:] = rsqrt(de) * sum_{v in e} rsqrt(dv) * Xh[v,:]  (64 thr, float4) ----
__global__ __launch_bounds__(64) void edge_gather(const float* __restrict__ Xh,
                                                  const int* __restrict__ edge_cnt,
                                                  const int* __restrict__ edge_list,
                                                  const int* __restrict__ node_cnt,
                                                  float* __restrict__ Y) {
    int e = blockIdx.x;
    int tid = threadIdx.x;
    __shared__ int   lv[CAP_E];
    __shared__ float lc[CAP_E];
    int cnt = min(edge_cnt[e], CAP_E);
    for (int j = tid; j < cnt; j += 64) {
        int v = edge_list[e * CAP_E + j];
        lv[j] = v * (DH / 4);
        lc[j] = rsqrtf((float)node_cnt[v]);
    }
    __syncthreads();
    const float4* X4 = (const float4*)Xh;
    float4 a0 = {0,0,0,0}, a1 = {0,0,0,0}, a2 = {0,0,0,0}, a3 = {0,0,0,0};
    int i = 0;
    for (; i + 4 <= cnt; i += 4) {
        float4 x0 = X4[lv[i+0] + tid], x1 = X4[lv[i+1] + tid];
        float4 x2 = X4[lv[i+2] + tid], x3 = X4[lv[i+3] + tid];
        float c0 = lc[i+0], c1 = lc[i+1], c2 = lc[i+2], c3 = lc[i+3];
        a0.x = fmaf(c0, x0.x, a0.x); a0.y = fmaf(c0, x0.y, a0.y);
        a0.z = fmaf(c0, x0.z, a0.z); a0.w = fmaf(c0, x0.w, a0.w);
        a1.x = fmaf(c1, x1.x, a1.x); a1.y = fmaf(c1, x1.y, a1.y);
        a1.z = fmaf(c1, x1.z, a1.z); a1.w = fmaf(c1, x1.w, a1.w);
        a2.x = fmaf(c2, x2.x, a2.x); a2.y = fmaf(c2, x2.y, a2.y);
        a2.z = fmaf(c2, x2.z, a2.z); a2.w = fmaf(c2, x2.w, a2.w);
        a3.x = fmaf(c3, x3.x, a3.x); a3.y = fmaf(c3, x3.y, a3.y);
        a3.z = fmaf(c3, x3.z, a3.z); a3.w = fmaf(c3, x3.w, a3.w);
    }
    for (; i < cnt; ++i) {
        float4 x0 = X4[lv[i] + tid]; float c0 = lc[i];
        a0.x = fmaf(c0, x0.x, a0.x); a0.y = fmaf(c0, x0.y, a0.y);
        a0.z = fmaf(c0, x0.z, a0.z); a0.w = fmaf(c0, x0.w, a0.w);
    }
    float de = cnt > 0 ? rsqrtf((float)cnt) : 0.f;
    float4 o;
    o.x = de * ((a0.x + a1.x) + (a2.x + a3.x));
    o.y = de * ((a0.y + a1.y) + (a2.y + a3.y));
    o.z = de * ((a0.z + a1.z) + (a2.z + a3.z));
    o.w = de * ((a0.w + a1.w) + (a2.w + a3.w));
    ((float4*)Y)[e * (DH / 4) + tid] = o;
}

// ---- Z[v,:] = rsqrt(dv) * sum_{e ∋ v} rsqrt(de) * Y[e,:]  (64 thr, float4) ----
__global__ __launch_bounds__(64) void node_gather(const float* __restrict__ Y,
                                                  const int* __restrict__ node_cnt,
                                                  const int* __restrict__ node_list,
                                                  const int* __restrict__ edge_cnt,
                                                  float* __restrict__ Z) {
    int v = blockIdx.x;
    int tid = threadIdx.x;
    __shared__ int   le[CAP_V];
    __shared__ float lc[CAP_V];
    int cnt = min(node_cnt[v], CAP_V);
    if (tid < cnt) {
        int e = node_list[v * CAP_V + tid];
        le[tid] = e * (DH / 4);
        lc[tid] = rsqrtf((float)edge_cnt[e]);
    }
    __syncthreads();
    const float4* Y4 = (const float4*)Y;
    float4 a0 = {0,0,0,0}, a1 = {0,0,0,0}, a2 = {0,0,0,0}, a3 = {0,0,0,0};
    int i = 0;
    for (; i + 4 <= cnt; i += 4) {
        float4 x0 = Y4[le[i+0] + tid], x1 = Y4[le[i+1] + tid];
        float4 x2 = Y4[le[i+2] + tid], x3 = Y4[le[i+3] + tid];
        float c0 = lc[i+0], c1 = lc[i+1], c2 = lc[i+2], c3 = lc[i+3];
        a0.x = fmaf(c0, x0.x, a0.x); a0.y = fmaf(c0, x0.y, a0.y);
        a0.z = fmaf(c0, x0.z, a0.z); a0.w = fmaf(c0, x0.w, a0.w);
        a1.x = fmaf(c1, x1.x, a1.x); a1.y = fmaf(c1, x1.y, a1.y);
        a1.z = fmaf(c1, x1.z, a1.z); a1.w = fmaf(c1, x1.w, a1.w);
        a2.x = fmaf(c2, x2.x, a2.x); a2.y = fmaf(c2, x2.y, a2.y);
        a2.z = fmaf(c2, x2.z, a2.z); a2.w = fmaf(c2, x2.w, a2.w);
        a3.x = fmaf(c3, x3.x, a3.x); a3.y = fmaf(c3, x3.y, a3.y);
        a3.z = fmaf(c3, x3.z, a3.z); a3.w = fmaf(c3, x3.w, a3.w);
    }
    for (; i < cnt; ++i) {
        float4 x0 = Y4[le[i] + tid]; float c0 = lc[i];
        a0.x = fmaf(c0, x0.x, a0.x); a0.y = fmaf(c0, x0.y, a0.y);
        a0.z = fmaf(c0, x0.z, a0.z); a0.w = fmaf(c0, x0.w, a0.w);
    }
    float dv = cnt > 0 ? rsqrtf((float)cnt) : 0.f;
    float4 o;
    o.x = dv * ((a0.x + a1.x) + (a2.x + a3.x));
    o.y = dv * ((a0.y + a1.y) + (a2.y + a3.y));
    o.z = dv * ((a0.z + a1.z) + (a2.z + a3.z));
    o.w = dv * ((a0.w + a1.w) + (a2.w + a3.w));
    ((float4*)Z)[v * (DH / 4) + tid] = o;
}

// ---------------- fused mean-pool + classifier + softmax (64 thr) ----------------
__global__ __launch_bounds__(64) void pool_classify(const float* __restrict__ Xh,
                                                    const int* __restrict__ edge_cnt,
                                                    const int* __restrict__ edge_list,
                                                    const float* __restrict__ Wc,
                                                    const float* __restrict__ bc,
                                                    float* __restrict__ out) {
    int e = blockIdx.x;
    int tid = threadIdx.x;
    __shared__ int lv[CAP_E];
    int cnt = min(edge_cnt[e], CAP_E);
    for (int j = tid; j < cnt; j += 64) lv[j] = edge_list[e * CAP_E + j] * (DH / 4);
    __syncthreads();
    const float4* X4 = (const float4*)Xh;
    float4 a0 = {0,0,0,0}, a1 = {0,0,0,0}, a2 = {0,0,0,0}, a3 = {0,0,0,0};
    int i = 0;
    for (; i + 4 <= cnt; i += 4) {
        float4 x0 = X4[lv[i+0] + tid], x1 = X4[lv[i+1] + tid];
        float4 x2 = X4[lv[i+2] + tid], x3 = X4[lv[i+3] + tid];
        a0.x += x0.x; a0.y += x0.y; a0.z += x0.z; a0.w += x0.w;
        a1.x += x1.x; a1.y += x1.y; a1.z += x1.z; a1.w += x1.w;
        a2.x += x2.x; a2.y += x2.y; a2.z += x2.z; a2.w += x2.w;
        a3.x += x3.x; a3.y += x3.y; a3.z += x3.z; a3.w += x3.w;
    }
    for (; i < cnt; ++i) {
        float4 x0 = X4[lv[i] + tid];
        a0.x += x0.x; a0.y += x0.y; a0.z += x0.z; a0.w += x0.w;
    }
    float inv = cnt > 0 ? 1.0f / (float)cnt : 1.0f;
    float4 val;
    val.x = inv * ((a0.x + a1.x) + (a2.x + a3.x));
    val.y = inv * ((a0.y + a1.y) + (a2.y + a3.y));
    val.z = inv * ((a0.z + a1.z) + (a2.z + a3.z));
    val.w = inv * ((a0.w + a1.w) + (a2.w + a3.w));
    const float4* W4 = (const float4*)Wc;
    float4 w0 = W4[tid], w1 = W4[64 + tid];
    float p0 = val.x * w0.x + val.y * w0.y + val.z * w0.z + val.w * w0.w;
    float p1 = val.x * w1.x + val.y * w1.y + val.z * w1.z + val.w * w1.w;
#pragma unroll
    for (int o = 32; o > 0; o >>= 1) {
        p0 += __shfl_down(p0, o, 64);
        p1 += __shfl_down(p1, o, 64);
    }
    if (tid == 0) {
        float l0 = p0 + bc[0], l1 = p1 + bc[1];
        float mx = fmaxf(l0, l1);
        float e0 = expf(l0 - mx), e1 = expf(l1 - mx);
        float s = 1.0f / (e0 + e1);
        out[e * 2 + 0] = e0 * s;
        out[e * 2 + 1] = e1 * s;
    }
}

extern "C" void kernel_launch(void* const* d_in, const int* in_sizes, int n_in,
                              void* d_out, int out_size, void* d_ws, size_t ws_size,
                              hipStream_t stream) {
    const float* X  = (const float*)d_in[0];
    const float* H  = (const float*)d_in[1];
    const float* Wp = (const float*)d_in[2];
    const float* W0 = (const float*)d_in[3];
    const float* W1 = (const float*)d_in[4];
    const float* g0 = (const float*)d_in[5];
    const float* b0 = (const float*)d_in[6];
    const float* g1 = (const float*)d_in[7];
    const float* b1 = (const float*)d_in[8];
    const float* Wc = (const float*)d_in[9];
    const float* bc = (const float*)d_in[10];
    float* out = (float*)d_out;

    float* ws = (float*)d_ws;
    float* Xh  = ws + OFF_XH;
    float* Z   = ws + OFF_Z;
    float* Y   = ws + OFF_Y;
    int* node_cnt  = (int*)(ws + OFF_NCNT);
    int* edge_cnt  = (int*)(ws + OFF_ECNT);
    int* edge_list = (int*)(ws + OFF_EL);
    int* node_list = (int*)(ws + OFF_NL);

    hipMemsetAsync(node_cnt, 0, (size_t)(NV + NE) * sizeof(int), stream);

    scan_H<<<(NV * NE) / 4096, 256, 0, stream>>>(H, edge_cnt, node_cnt, edge_list, node_list);

    // Xh = X @ Wp^T
    gemm_bf16<<<NV / 32, 256, 0, stream>>>(X, Wp, Xh, DIN);

    const float* Ws[2] = {W0, W1};
    const float* gs[2] = {g0, g1};
    const float* bs[2] = {b0, b1};
    for (int l = 0; l < 2; ++l) {
        edge_gather<<<NE, 64, 0, stream>>>(Xh, edge_cnt, edge_list, node_cnt, Y);
        node_gather<<<NV, 64, 0, stream>>>(Y, node_cnt, node_list, edge_cnt, Z);
        gemm_relu_res_ln<<<NV / 32, 256, 0, stream>>>(Z, Ws[l], Xh, gs[l], bs[l]);
    }

    pool_classify<<<NE, 64, 0, stream>>>(Xh, edge_cnt, edge_list, Wc, bc, out);
}

// Round 4
// 327.783 us; speedup vs baseline: 1.2549x; 1.0058x over previous
//
#include <hip/hip_runtime.h>
#include <math.h>

#define NV 8192
#define NE 4096
#define DIN 512
#define DH 256
#define CAP_E 96
#define CAP_V 64

// ---------------- workspace layout (float offsets) ----------------
// edge_cnt is PADDED: one counter per 16 dwords (64B line) to kill
// cross-XCD same-line atomic serialization.
#define OFF_XH   0                       // V*DH
#define OFF_Z    (OFF_XH + NV*DH)        // V*DH
#define OFF_Y    (OFF_Z  + NV*DH)        // E*DH
#define OFF_NCNT (OFF_Y  + NE*DH)        // V ints (no atomics, written once)
#define OFF_ECNT (OFF_NCNT + NV)         // E*16 ints (padded)
#define OFF_EL   (OFF_ECNT + NE*16)      // E*CAP_E ints
#define OFF_NL   (OFF_EL + NE*CAP_E)     // V*CAP_V ints

using bf16x8 = __attribute__((ext_vector_type(8))) short;
using f32x4  = __attribute__((ext_vector_type(4))) float;

__device__ inline unsigned short f2bf(float f) {   // round-to-nearest-even
    union { float f; unsigned u; } v; v.f = f;
    unsigned r = v.u + 0x7FFF + ((v.u >> 16) & 1);
    return (unsigned short)(r >> 16);
}

// ---------------- build sparse adjacency from dense H ----------------
// One block per row v. Node side: LDS aggregation, ZERO global atomics.
// Edge side: return-atomic per member to line-padded counters.
__global__ __launch_bounds__(256) void scan_H(const float* __restrict__ H,
                                              int* __restrict__ edge_cnt,   // stride 16
                                              int* __restrict__ node_cnt,
                                              int* __restrict__ edge_list,
                                              int* __restrict__ node_list) {
    int v = blockIdx.x;
    int t = threadIdx.x;
    __shared__ int lcnt;
    __shared__ int lbuf[CAP_V];
    if (t == 0) lcnt = 0;
    __syncthreads();
    const float4* H4 = (const float4*)(H + (size_t)v * NE);
    float4 h0 = H4[t * 4 + 0], h1 = H4[t * 4 + 1];
    float4 h2 = H4[t * 4 + 2], h3 = H4[t * 4 + 3];
    float hv[16] = {h0.x, h0.y, h0.z, h0.w, h1.x, h1.y, h1.z, h1.w,
                    h2.x, h2.y, h2.z, h2.w, h3.x, h3.y, h3.z, h3.w};
    int myE[16]; int n = 0;
    int e0 = t * 16;
#pragma unroll
    for (int j = 0; j < 16; ++j)
        if (hv[j] != 0.0f) myE[n++] = e0 + j;
    if (n > 0) {
        int s = atomicAdd(&lcnt, n);
        for (int k = 0; k < n; ++k) {
            int ee = myE[k];
            if (s + k < CAP_V) lbuf[s + k] = ee;
            int g = atomicAdd(&edge_cnt[ee << 4], 1);
            if (g < CAP_E) edge_list[ee * CAP_E + g] = v;
        }
    }
    __syncthreads();
    int c = lcnt;
    if (t == 0) node_cnt[v] = c;          // true degree, non-atomic
    c = min(c, CAP_V);
    for (int i = t; i < c; i += 256) node_list[v * CAP_V + i] = lbuf[i];
}

// ---------------- bf16 MFMA GEMM (plain): C[M,256] = A[M,K] @ B[256,K]^T ------
__global__ __launch_bounds__(256) void gemm_bf16(const float* __restrict__ A,
                                                 const float* __restrict__ B,
                                                 float* __restrict__ C,
                                                 int K) {
    __shared__ short As[2048];
    __shared__ short Bs[16384];
    const int tid  = threadIdx.x;
    const int lane = tid & 63;
    const int w    = tid >> 6;
    const int bm   = blockIdx.x * 32;
    const int swz  = lane ^ ((lane >> 3) & 6);

    float4 ar[2], br[16];
    {
        int i0 = tid, i1 = tid + 256;
        ar[0] = *(const float4*)(A + (size_t)(bm + (i0 >> 4)) * K + ((i0 & 15) << 2));
        ar[1] = *(const float4*)(A + (size_t)(bm + (i1 >> 4)) * K + ((i1 & 15) << 2));
#pragma unroll
        for (int it = 0; it < 16; ++it) {
            int i = tid + it * 256;
            br[it] = *(const float4*)(B + (size_t)(i >> 4) * K + ((i & 15) << 2));
        }
    }
    f32x4 acc[2][4];
#pragma unroll
    for (int mi = 0; mi < 2; ++mi)
#pragma unroll
        for (int ni = 0; ni < 4; ++ni) acc[mi][ni] = (f32x4){0.f, 0.f, 0.f, 0.f};

    for (int k0 = 0; k0 < K; k0 += 64) {
        __syncthreads();
#pragma unroll
        for (int s = 0; s < 2; ++s) {
            int i = tid + s * 256;
            int row = i >> 4, kk = (i & 15) << 2;
            int kc = kk >> 5, quad = (kk >> 3) & 3, j = kk & 7;
            int ln = (row & 15) + (quad << 4);
            int p  = ln ^ ((ln >> 3) & 6);
            int addr = ((row >> 4) * 2 + kc) * 512 + p * 8 + j;
            float4 v = ar[s];
            ushort4 u = {f2bf(v.x), f2bf(v.y), f2bf(v.z), f2bf(v.w)};
            *(ushort4*)&As[addr] = u;
        }
#pragma unroll
        for (int it = 0; it < 16; ++it) {
            int i = tid + it * 256;
            int row = i >> 4, kk = (i & 15) << 2;
            int kc = kk >> 5, quad = (kk >> 3) & 3, j = kk & 7;
            int ln = (row & 15) + (quad << 4);
            int p  = ln ^ ((ln >> 3) & 6);
            int addr = ((row >> 4) * 2 + kc) * 512 + p * 8 + j;
            float4 v = br[it];
            ushort4 u = {f2bf(v.x), f2bf(v.y), f2bf(v.z), f2bf(v.w)};
            *(ushort4*)&Bs[addr] = u;
        }
        __syncthreads();
        if (k0 + 64 < K) {
            int kn = k0 + 64;
            int i0 = tid, i1 = tid + 256;
            ar[0] = *(const float4*)(A + (size_t)(bm + (i0 >> 4)) * K + kn + ((i0 & 15) << 2));
            ar[1] = *(const float4*)(A + (size_t)(bm + (i1 >> 4)) * K + kn + ((i1 & 15) << 2));
#pragma unroll
            for (int it = 0; it < 16; ++it) {
                int i = tid + it * 256;
                br[it] = *(const float4*)(B + (size_t)(i >> 4) * K + kn + ((i & 15) << 2));
            }
        }
#pragma unroll
        for (int kc = 0; kc < 2; ++kc) {
            bf16x8 af[2], bfr[4];
            af[0] = *(const bf16x8*)&As[(0 * 2 + kc) * 512 + swz * 8];
            af[1] = *(const bf16x8*)&As[(1 * 2 + kc) * 512 + swz * 8];
#pragma unroll
            for (int ni = 0; ni < 4; ++ni)
                bfr[ni] = *(const bf16x8*)&Bs[((w * 4 + ni) * 2 + kc) * 512 + swz * 8];
#pragma unroll
            for (int mi = 0; mi < 2; ++mi)
#pragma unroll
                for (int ni = 0; ni < 4; ++ni)
                    acc[mi][ni] = __builtin_amdgcn_mfma_f32_16x16x32_bf16(
                        af[mi], bfr[ni], acc[mi][ni], 0, 0, 0);
        }
    }
    const int quad = lane >> 4, cl = lane & 15;
#pragma unroll
    for (int mi = 0; mi < 2; ++mi)
#pragma unroll
        for (int ni = 0; ni < 4; ++ni)
#pragma unroll
            for (int r = 0; r < 4; ++r)
                C[(size_t)(bm + mi * 16 + quad * 4 + r) * DH + w * 64 + ni * 16 + cl]
                    = acc[mi][ni][r];
}

// ------- fused: Xh = LayerNorm(Xh + relu(Z @ W^T)) * g + b  (K=256) ----------
__global__ __launch_bounds__(256) void gemm_relu_res_ln(const float* __restrict__ Z,
                                                        const float* __restrict__ W,
                                                        float* __restrict__ Xh,
                                                        const float* __restrict__ g,
                                                        const float* __restrict__ b) {
    const int K = DH;
    __shared__ short As[2048];
    __shared__ short Bs[16384];
    __shared__ float redS[32][4];
    __shared__ float redQ[32][4];
    const int tid  = threadIdx.x;
    const int lane = tid & 63;
    const int w    = tid >> 6;
    const int bm   = blockIdx.x * 32;
    const int swz  = lane ^ ((lane >> 3) & 6);

    float4 ar[2], br[16];
    {
        int i0 = tid, i1 = tid + 256;
        ar[0] = *(const float4*)(Z + (size_t)(bm + (i0 >> 4)) * K + ((i0 & 15) << 2));
        ar[1] = *(const float4*)(Z + (size_t)(bm + (i1 >> 4)) * K + ((i1 & 15) << 2));
#pragma unroll
        for (int it = 0; it < 16; ++it) {
            int i = tid + it * 256;
            br[it] = *(const float4*)(W + (size_t)(i >> 4) * K + ((i & 15) << 2));
        }
    }
    f32x4 acc[2][4];
#pragma unroll
    for (int mi = 0; mi < 2; ++mi)
#pragma unroll
        for (int ni = 0; ni < 4; ++ni) acc[mi][ni] = (f32x4){0.f, 0.f, 0.f, 0.f};

    for (int k0 = 0; k0 < K; k0 += 64) {
        __syncthreads();
#pragma unroll
        for (int s = 0; s < 2; ++s) {
            int i = tid + s * 256;
            int row = i >> 4, kk = (i & 15) << 2;
            int kc = kk >> 5, quad = (kk >> 3) & 3, j = kk & 7;
            int ln = (row & 15) + (quad << 4);
            int p  = ln ^ ((ln >> 3) & 6);
            int addr = ((row >> 4) * 2 + kc) * 512 + p * 8 + j;
            float4 v = ar[s];
            ushort4 u = {f2bf(v.x), f2bf(v.y), f2bf(v.z), f2bf(v.w)};
            *(ushort4*)&As[addr] = u;
        }
#pragma unroll
        for (int it = 0; it < 16; ++it) {
            int i = tid + it * 256;
            int row = i >> 4, kk = (i & 15) << 2;
            int kc = kk >> 5, quad = (kk >> 3) & 3, j = kk & 7;
            int ln = (row & 15) + (quad << 4);
            int p  = ln ^ ((ln >> 3) & 6);
            int addr = ((row >> 4) * 2 + kc) * 512 + p * 8 + j;
            float4 v = br[it];
            ushort4 u = {f2bf(v.x), f2bf(v.y), f2bf(v.z), f2bf(v.w)};
            *(ushort4*)&Bs[addr] = u;
        }
        __syncthreads();
        if (k0 + 64 < K) {
            int kn = k0 + 64;
            int i0 = tid, i1 = tid + 256;
            ar[0] = *(const float4*)(Z + (size_t)(bm + (i0 >> 4)) * K + kn + ((i0 & 15) << 2));
            ar[1] = *(const float4*)(Z + (size_t)(bm + (i1 >> 4)) * K + kn + ((i1 & 15) << 2));
#pragma unroll
            for (int it = 0; it < 16; ++it) {
                int i = tid + it * 256;
                br[it] = *(const float4*)(W + (size_t)(i >> 4) * K + kn + ((i & 15) << 2));
            }
        }
#pragma unroll
        for (int kc = 0; kc < 2; ++kc) {
            bf16x8 af[2], bfr[4];
            af[0] = *(const bf16x8*)&As[(0 * 2 + kc) * 512 + swz * 8];
            af[1] = *(const bf16x8*)&As[(1 * 2 + kc) * 512 + swz * 8];
#pragma unroll
            for (int ni = 0; ni < 4; ++ni)
                bfr[ni] = *(const bf16x8*)&Bs[((w * 4 + ni) * 2 + kc) * 512 + swz * 8];
#pragma unroll
            for (int mi = 0; mi < 2; ++mi)
#pragma unroll
                for (int ni = 0; ni < 4; ++ni)
                    acc[mi][ni] = __builtin_amdgcn_mfma_f32_16x16x32_bf16(
                        af[mi], bfr[ni], acc[mi][ni], 0, 0, 0);
        }
    }
    const int quad = lane >> 4, cl = lane & 15;
#pragma unroll
    for (int mi = 0; mi < 2; ++mi)
#pragma unroll
        for (int r = 0; r < 4; ++r) {
            int row = bm + mi * 16 + quad * 4 + r;
            float s = 0.f, q = 0.f;
#pragma unroll
            for (int ni = 0; ni < 4; ++ni) {
                int col = w * 64 + ni * 16 + cl;
                float v = fmaxf(acc[mi][ni][r], 0.f) + Xh[(size_t)row * DH + col];
                acc[mi][ni][r] = v;
                s += v; q = fmaf(v, v, q);
            }
#pragma unroll
            for (int o = 1; o < 16; o <<= 1) {
                s += __shfl_xor(s, o, 64);
                q += __shfl_xor(q, o, 64);
            }
            if (cl == 0) {
                redS[mi * 16 + quad * 4 + r][w] = s;
                redQ[mi * 16 + quad * 4 + r][w] = q;
            }
        }
    __syncthreads();
#pragma unroll
    for (int mi = 0; mi < 2; ++mi)
#pragma unroll
        for (int r = 0; r < 4; ++r) {
            int R = mi * 16 + quad * 4 + r;
            float s = redS[R][0] + redS[R][1] + redS[R][2] + redS[R][3];
            float q = redQ[R][0] + redQ[R][1] + redQ[R][2] + redQ[R][3];
            float m = s * (1.0f / DH);
            float var = q * (1.0f / DH) - m * m;
            float rstd = rsqrtf(var + 1e-5f);
            int row = bm + R;
#pragma unroll
            for (int ni = 0; ni < 4; ++ni) {
                int col = w * 64 + ni * 16 + cl;
                float v = (acc[mi][ni][r] - m) * rstd * g[col] + b[col];
                Xh[(size_t)row * DH + col] = v;
            }
        }
}

#define GATHER_BODY(SRC, IDX, COEF, CNT)                                         \
    float4 a[8];                                                                 \
    _Pragma("unroll") for (int u = 0; u < 8; ++u) a[u] = (float4){0,0,0,0};      \
    int i = 0;                                                                   \
    for (; i + 8 <= CNT; i += 8) {                                               \
        _Pragma("unroll") for (int u = 0; u < 8; ++u) {                          \
            float4 x = SRC[IDX[i+u] + tid]; float c = COEF[i+u];                 \
            a[u].x = fmaf(c, x.x, a[u].x); a[u].y = fmaf(c, x.y, a[u].y);        \
            a[u].z = fmaf(c, x.z, a[u].z); a[u].w = fmaf(c, x.w, a[u].w);        \
        }                                                                        \
    }                                                                            \
    for (; i < CNT; ++i) {                                                       \
        float4 x = SRC[IDX[i] + tid]; float c = COEF[i];                         \
        a[0].x = fmaf(c, x.x, a[0].x); a[0].y = fmaf(c, x.y, a[0].y);            \
        a[0].z = fmaf(c, x.z, a[0].z); a[0].w = fmaf(c, x.w, a[0].w);            \
    }                                                                            \
    _Pragma("unroll") for (int u = 4; u > 0; u >>= 1)                            \
        _Pragma("unroll") for (int q = 0; q < u; ++q) {                          \
            a[q].x += a[q+u].x; a[q].y += a[q+u].y;                              \
            a[q].z += a[q+u].z; a[q].w += a[q+u].w;                              \
        }

// ---- Y[e,:] = rsqrt(de) * sum_{v in e} rsqrt(dv) * Xh[v,:]  (64 thr) ----
__global__ __launch_bounds__(64) void edge_gather(const float* __restrict__ Xh,
                                                  const int* __restrict__ edge_cnt,
                                                  const int* __restrict__ edge_list,
                                                  const int* __restrict__ node_cnt,
                                                  float* __restrict__ Y) {
    int e = blockIdx.x;
    int tid = threadIdx.x;
    __shared__ int   lv[CAP_E];
    __shared__ float lc[CAP_E];
    int cnt = min(edge_cnt[e << 4], CAP_E);
    for (int j = tid; j < cnt; j += 64) {
        int v = edge_list[e * CAP_E + j];
        lv[j] = v * (DH / 4);
        lc[j] = rsqrtf((float)node_cnt[v]);
    }
    __syncthreads();
    const float4* X4 = (const float4*)Xh;
    GATHER_BODY(X4, lv, lc, cnt)
    float de = cnt > 0 ? rsqrtf((float)cnt) : 0.f;
    float4 o = {de * a[0].x, de * a[0].y, de * a[0].z, de * a[0].w};
    ((float4*)Y)[e * (DH / 4) + tid] = o;
}

// ---- Z[v,:] = rsqrt(dv) * sum_{e ∋ v} rsqrt(de) * Y[e,:]  (64 thr) ----
__global__ __launch_bounds__(64) void node_gather(const float* __restrict__ Y,
                                                  const int* __restrict__ node_cnt,
                                                  const int* __restrict__ node_list,
                                                  const int* __restrict__ edge_cnt,
                                                  float* __restrict__ Z) {
    int v = blockIdx.x;
    int tid = threadIdx.x;
    __shared__ int   le[CAP_V];
    __shared__ float lc[CAP_V];
    int cnt = min(node_cnt[v], CAP_V);
    if (tid < cnt) {
        int e = node_list[v * CAP_V + tid];
        le[tid] = e * (DH / 4);
        lc[tid] = rsqrtf((float)edge_cnt[e << 4]);
    }
    __syncthreads();
    const float4* Y4 = (const float4*)Y;
    GATHER_BODY(Y4, le, lc, cnt)
    float dv = cnt > 0 ? rsqrtf((float)cnt) : 0.f;
    float4 o = {dv * a[0].x, dv * a[0].y, dv * a[0].z, dv * a[0].w};
    ((float4*)Z)[v * (DH / 4) + tid] = o;
}

// ---------------- fused mean-pool + classifier + softmax (64 thr) ----------------
__global__ __launch_bounds__(64) void pool_classify(const float* __restrict__ Xh,
                                                    const int* __restrict__ edge_cnt,
                                                    const int* __restrict__ edge_list,
                                                    const float* __restrict__ Wc,
                                                    const float* __restrict__ bc,
                                                    float* __restrict__ out) {
    int e = blockIdx.x;
    int tid = threadIdx.x;
    __shared__ int lv[CAP_E];
    int cnt = min(edge_cnt[e << 4], CAP_E);
    for (int j = tid; j < cnt; j += 64) lv[j] = edge_list[e * CAP_E + j] * (DH / 4);
    __syncthreads();
    const float4* X4 = (const float4*)Xh;
    float4 a[8];
#pragma unroll
    for (int u = 0; u < 8; ++u) a[u] = (float4){0, 0, 0, 0};
    int i = 0;
    for (; i + 8 <= cnt; i += 8) {
#pragma unroll
        for (int u = 0; u < 8; ++u) {
            float4 x = X4[lv[i + u] + tid];
            a[u].x += x.x; a[u].y += x.y; a[u].z += x.z; a[u].w += x.w;
        }
    }
    for (; i < cnt; ++i) {
        float4 x = X4[lv[i] + tid];
        a[0].x += x.x; a[0].y += x.y; a[0].z += x.z; a[0].w += x.w;
    }
#pragma unroll
    for (int u = 4; u > 0; u >>= 1)
#pragma unroll
        for (int q = 0; q < u; ++q) {
            a[q].x += a[q + u].x; a[q].y += a[q + u].y;
            a[q].z += a[q + u].z; a[q].w += a[q + u].w;
        }
    float inv = cnt > 0 ? 1.0f / (float)cnt : 1.0f;
    float4 val = {a[0].x * inv, a[0].y * inv, a[0].z * inv, a[0].w * inv};
    const float4* W4 = (const float4*)Wc;
    float4 w0 = W4[tid], w1 = W4[64 + tid];
    float p0 = val.x * w0.x + val.y * w0.y + val.z * w0.z + val.w * w0.w;
    float p1 = val.x * w1.x + val.y * w1.y + val.z * w1.z + val.w * w1.w;
#pragma unroll
    for (int o = 32; o > 0; o >>= 1) {
        p0 += __shfl_down(p0, o, 64);
        p1 += __shfl_down(p1, o, 64);
    }
    if (tid == 0) {
        float l0 = p0 + bc[0], l1 = p1 + bc[1];
        float mx = fmaxf(l0, l1);
        float e0 = expf(l0 - mx), e1 = expf(l1 - mx);
        float s = 1.0f / (e0 + e1);
        out[e * 2 + 0] = e0 * s;
        out[e * 2 + 1] = e1 * s;
    }
}

extern "C" void kernel_launch(void* const* d_in, const int* in_sizes, int n_in,
                              void* d_out, int out_size, void* d_ws, size_t ws_size,
                              hipStream_t stream) {
    const float* X  = (const float*)d_in[0];
    const float* H  = (const float*)d_in[1];
    const float* Wp = (const float*)d_in[2];
    const float* W0 = (const float*)d_in[3];
    const float* W1 = (const float*)d_in[4];
    const float* g0 = (const float*)d_in[5];
    const float* b0 = (const float*)d_in[6];
    const float* g1 = (const float*)d_in[7];
    const float* b1 = (const float*)d_in[8];
    const float* Wc = (const float*)d_in[9];
    const float* bc = (const float*)d_in[10];
    float* out = (float*)d_out;

    float* ws = (float*)d_ws;
    float* Xh  = ws + OFF_XH;
    float* Z   = ws + OFF_Z;
    float* Y   = ws + OFF_Y;
    int* node_cnt  = (int*)(ws + OFF_NCNT);
    int* edge_cnt  = (int*)(ws + OFF_ECNT);
    int* edge_list = (int*)(ws + OFF_EL);
    int* node_list = (int*)(ws + OFF_NL);

    // only the padded edge counters need zeroing (node_cnt written directly)
    hipMemsetAsync(edge_cnt, 0, (size_t)(NE * 16) * sizeof(int), stream);

    scan_H<<<NV, 256, 0, stream>>>(H, edge_cnt, node_cnt, edge_list, node_list);

    // Xh = X @ Wp^T
    gemm_bf16<<<NV / 32, 256, 0, stream>>>(X, Wp, Xh, DIN);

    const float* Ws[2] = {W0, W1};
    const float* gs[2] = {g0, g1};
    const float* bs[2] = {b0, b1};
    for (int l = 0; l < 2; ++l) {
        edge_gather<<<NE, 64, 0, stream>>>(Xh, edge_cnt, edge_list, node_cnt, Y);
        node_gather<<<NV, 64, 0, stream>>>(Y, node_cnt, node_list, edge_cnt, Z);
        gemm_relu_res_ln<<<NV / 32, 256, 0, stream>>>(Z, Ws[l], Xh, gs[l], bs[l]);
    }

    pool_classify<<<NE, 64, 0, stream>>>(Xh, edge_cnt, edge_list, Wc, bc, out);
}